// Round 1
// baseline (323.090 us; speedup 1.0000x reference)
//
#include <hip/hip_runtime.h>

// Swin cross-attention fused kernel for MI355X.
// C=256, HEADS=2, dh=128, WS=8, T=64 tokens/window.
// Phase A: f1' = relu(f1 + SCA(f1, f2, w1[lvl]));  Phase B: f2' = relu(f2 + SCA(f2, f1', w2[lvl]))
// One block per window (64 tokens x 256 ch), 4 waves, all GEMMs via mfma_f32_16x16x32_bf16.

using bf16x8 = __attribute__((ext_vector_type(8))) __bf16;
using f32x4  = __attribute__((ext_vector_type(4))) float;
using u16x4  = __attribute__((ext_vector_type(4))) unsigned short;
using u16x8  = __attribute__((ext_vector_type(8))) unsigned short;

__device__ __forceinline__ unsigned short f2bf(float f){
  unsigned int x = __float_as_uint(f);
  x += 0x7FFFu + ((x >> 16) & 1u);          // RNE
  return (unsigned short)(x >> 16);
}

__device__ __forceinline__ void store_bf4(unsigned short* dst, f32x4 v){
  u16x4 o;
  o[0]=f2bf(v[0]); o[1]=f2bf(v[1]); o[2]=f2bf(v[2]); o[3]=f2bf(v[3]);
  *reinterpret_cast<u16x4*>(dst) = o;       // 8B packed store
}

#define MFMA16 __builtin_amdgcn_mfma_f32_16x16x32_bf16

__global__ void wcvt_kernel(const float* __restrict__ w1,
                            const float* __restrict__ w2,
                            unsigned short* __restrict__ dst){
  int i = blockIdx.x * 256 + threadIdx.x;   // 524288 float4s total
  const float4* src = (i < 262144) ? (reinterpret_cast<const float4*>(w1) + i)
                                   : (reinterpret_cast<const float4*>(w2) + (i - 262144));
  float4 v = *src;
  u16x4 o; o[0]=f2bf(v.x); o[1]=f2bf(v.y); o[2]=f2bf(v.z); o[3]=f2bf(v.w);
  reinterpret_cast<u16x4*>(dst)[i] = o;
}

__global__ __launch_bounds__(256, 1) void swin_phase(
    const float* __restrict__ g0, const float* __restrict__ g1,
    const float* __restrict__ g2, const float* __restrict__ g3,
    const unsigned short* __restrict__ wball,
    float* __restrict__ outb, int phase)
{
  // LDS pool (aliased lifetimes):
  // R0: Y(stage) -> X(stage) -> O(PV out)   [64][264] bf16
  // R1: K[u][d]  -> P[h][t][u] (subset)     [64][264] bf16
  // R2: V[d][u]                             [256][72] bf16
  // R3: Q[t][d]                             [64][264] bf16
  __shared__ alignas(16) unsigned short R0[64*264];
  __shared__ alignas(16) unsigned short R1[64*264];
  __shared__ alignas(16) unsigned short R2[256*72];
  __shared__ alignas(16) unsigned short R3[64*264];

  int bid = blockIdx.x;
  int lvl, wloc;
  if (bid < 512){ lvl = 0; wloc = bid; }
  else if (bid < 640){ lvl = 1; wloc = bid - 512; }
  else if (bid < 672){ lvl = 2; wloc = bid - 640; }
  else { lvl = 3; wloc = bid - 672; }

  int H; size_t ooff; const float* feat;
  if (lvl == 0){ H = 128; ooff = 0;        feat = g0; }
  else if (lvl == 1){ H = 64; ooff = 16777216; feat = g1; }
  else if (lvl == 2){ H = 32; ooff = 20971520; feat = g2; }
  else { H = 16; ooff = 22020096; feat = g3; }

  int W = H, nww = H >> 3, npb = nww * nww;
  int b = wloc / npb, r = wloc - b * npb;
  int whh = r / nww, www = r - whh * nww;
  size_t HW = (size_t)H * W, CHW = HW * 256;
  size_t winoff = (size_t)(whh * 8) * W + (size_t)(www * 8);

  const float* xsrc; const float* ysrc; float* outp;
  if (phase == 0){
    xsrc = feat + (size_t)b * CHW + winoff;          // f1
    ysrc = feat + (size_t)(b + 2) * CHW + winoff;    // f2
    outp = outb + ooff + (size_t)b * CHW + winoff;   // f1'
  } else {
    xsrc = feat + (size_t)(b + 2) * CHW + winoff;    // f2
    ysrc = outb + ooff + (size_t)b * CHW + winoff;   // f1' (written by phase A)
    outp = outb + ooff + (size_t)(b + 2) * CHW + winoff;
  }
  const unsigned short* Wq = wball + ((size_t)(phase * 16 + lvl * 4) << 16);
  const unsigned short* Wk = Wq + 65536;
  const unsigned short* Wv = Wq + 2 * 65536;
  const unsigned short* Wo = Wq + 3 * 65536;

  int tid = threadIdx.x;
  int w   = tid >> 6, l = tid & 63, l15 = l & 15, l4 = l >> 4;
  int hi0 = l >> 3, wi0 = l & 7;
  int wd  = w * 64;

  // ---------------- stage Y (yw, bf16, [t][c] pad 264) into R0 ----------------
  {
    const float* p0 = ysrc + (size_t)hi0 * W + wi0;
    #pragma unroll
    for (int oc = 0; oc < 8; ++oc){
      int c0 = (oc * 4 + w) * 8;
      const float* p = p0 + (size_t)c0 * HW;
      u16x8 uv;
      #pragma unroll
      for (int j = 0; j < 8; ++j) uv[j] = f2bf(p[(size_t)j * HW]);
      *reinterpret_cast<u16x8*>(&R0[l * 264 + c0]) = uv;
    }
  }
  __syncthreads();

  // ---------------- K^T = Wk * yw^T  -> K[u][d] in R1 ----------------
  {
    f32x4 acc[4][4];
    #pragma unroll
    for (int i = 0; i < 4; ++i)
      #pragma unroll
      for (int j = 0; j < 4; ++j) acc[i][j] = f32x4{0.f,0.f,0.f,0.f};
    #pragma unroll
    for (int ks = 0; ks < 8; ++ks){
      int k0 = ks * 32 + l4 * 8;
      bf16x8 a[4], bb[4];
      #pragma unroll
      for (int mi = 0; mi < 4; ++mi)
        a[mi] = *reinterpret_cast<const bf16x8*>(Wk + (size_t)((wd + mi*16 + l15) * 256 + k0));
      #pragma unroll
      for (int ni = 0; ni < 4; ++ni)
        bb[ni] = *reinterpret_cast<const bf16x8*>(&R0[(ni*16 + l15) * 264 + k0]);
      #pragma unroll
      for (int mi = 0; mi < 4; ++mi)
        #pragma unroll
        for (int ni = 0; ni < 4; ++ni)
          acc[mi][ni] = MFMA16(a[mi], bb[ni], acc[mi][ni], 0, 0, 0);
    }
    #pragma unroll
    for (int mi = 0; mi < 4; ++mi){
      int d0 = wd + mi*16 + l4*4;
      #pragma unroll
      for (int ni = 0; ni < 4; ++ni)
        store_bf4(&R1[(ni*16 + l15) * 264 + d0], acc[mi][ni]);
    }
  }

  // ---------------- V = yw * Wv^T  -> V[d][u] in R2 ----------------
  {
    f32x4 acc[4][4];
    #pragma unroll
    for (int i = 0; i < 4; ++i)
      #pragma unroll
      for (int j = 0; j < 4; ++j) acc[i][j] = f32x4{0.f,0.f,0.f,0.f};
    #pragma unroll
    for (int ks = 0; ks < 8; ++ks){
      int k0 = ks * 32 + l4 * 8;
      bf16x8 a[4], bb[4];
      #pragma unroll
      for (int mi = 0; mi < 4; ++mi)
        a[mi] = *reinterpret_cast<const bf16x8*>(&R0[(mi*16 + l15) * 264 + k0]);
      #pragma unroll
      for (int ni = 0; ni < 4; ++ni)
        bb[ni] = *reinterpret_cast<const bf16x8*>(Wv + (size_t)((wd + ni*16 + l15) * 256 + k0));
      #pragma unroll
      for (int mi = 0; mi < 4; ++mi)
        #pragma unroll
        for (int ni = 0; ni < 4; ++ni)
          acc[mi][ni] = MFMA16(a[mi], bb[ni], acc[mi][ni], 0, 0, 0);
    }
    #pragma unroll
    for (int mi = 0; mi < 4; ++mi){
      int u0 = mi*16 + l4*4;
      #pragma unroll
      for (int ni = 0; ni < 4; ++ni)
        store_bf4(&R2[(wd + ni*16 + l15) * 72 + u0], acc[mi][ni]);
    }
  }
  __syncthreads();   // Y fully consumed; safe to overwrite R0 with X

  // ---------------- stage X (xw) into R0 ----------------
  {
    const float* p0 = xsrc + (size_t)hi0 * W + wi0;
    #pragma unroll
    for (int oc = 0; oc < 8; ++oc){
      int c0 = (oc * 4 + w) * 8;
      const float* p = p0 + (size_t)c0 * HW;
      u16x8 uv;
      #pragma unroll
      for (int j = 0; j < 8; ++j) uv[j] = f2bf(p[(size_t)j * HW]);
      *reinterpret_cast<u16x8*>(&R0[l * 264 + c0]) = uv;
    }
  }
  __syncthreads();

  // ---------------- Q^T = Wq * xw^T -> Q[t][d] in R3 ----------------
  {
    f32x4 acc[4][4];
    #pragma unroll
    for (int i = 0; i < 4; ++i)
      #pragma unroll
      for (int j = 0; j < 4; ++j) acc[i][j] = f32x4{0.f,0.f,0.f,0.f};
    #pragma unroll
    for (int ks = 0; ks < 8; ++ks){
      int k0 = ks * 32 + l4 * 8;
      bf16x8 a[4], bb[4];
      #pragma unroll
      for (int mi = 0; mi < 4; ++mi)
        a[mi] = *reinterpret_cast<const bf16x8*>(Wq + (size_t)((wd + mi*16 + l15) * 256 + k0));
      #pragma unroll
      for (int ni = 0; ni < 4; ++ni)
        bb[ni] = *reinterpret_cast<const bf16x8*>(&R0[(ni*16 + l15) * 264 + k0]);
      #pragma unroll
      for (int mi = 0; mi < 4; ++mi)
        #pragma unroll
        for (int ni = 0; ni < 4; ++ni)
          acc[mi][ni] = MFMA16(a[mi], bb[ni], acc[mi][ni], 0, 0, 0);
    }
    #pragma unroll
    for (int mi = 0; mi < 4; ++mi){
      int d0 = wd + mi*16 + l4*4;
      #pragma unroll
      for (int ni = 0; ni < 4; ++ni)
        store_bf4(&R3[(ni*16 + l15) * 264 + d0], acc[mi][ni]);
    }
  }
  __syncthreads();

  // ---------------- S^T[u][t] per head + softmax over u -> P[h][t][u] ----------------
  int h = w >> 1, tc = w & 1;
  {
    f32x4 s[4][2];
    #pragma unroll
    for (int i = 0; i < 4; ++i){ s[i][0] = f32x4{0.f,0.f,0.f,0.f}; s[i][1] = f32x4{0.f,0.f,0.f,0.f}; }
    #pragma unroll
    for (int ks = 0; ks < 4; ++ks){
      int k0 = h * 128 + ks * 32 + l4 * 8;
      bf16x8 a[4], bb[2];
      #pragma unroll
      for (int mi = 0; mi < 4; ++mi)
        a[mi] = *reinterpret_cast<const bf16x8*>(&R1[(mi*16 + l15) * 264 + k0]);   // K[u][d]
      #pragma unroll
      for (int ni = 0; ni < 2; ++ni)
        bb[ni] = *reinterpret_cast<const bf16x8*>(&R3[(tc*32 + ni*16 + l15) * 264 + k0]); // Q[t][d]
      #pragma unroll
      for (int mi = 0; mi < 4; ++mi)
        #pragma unroll
        for (int ni = 0; ni < 2; ++ni)
          s[mi][ni] = MFMA16(a[mi], bb[ni], s[mi][ni], 0, 0, 0);
    }
    __syncthreads();   // K fully consumed; P may overwrite R1
    const float SCL = 0.08838834764831845f;   // 1/sqrt(128)
    unsigned short* P = R1;
    #pragma unroll
    for (int ni = 0; ni < 2; ++ni){
      float m = s[0][ni][0];
      #pragma unroll
      for (int mi = 0; mi < 4; ++mi)
        #pragma unroll
        for (int reg = 0; reg < 4; ++reg) m = fmaxf(m, s[mi][ni][reg]);
      m = fmaxf(m, __shfl_xor(m, 16));
      m = fmaxf(m, __shfl_xor(m, 32));
      float sum = 0.f;
      #pragma unroll
      for (int mi = 0; mi < 4; ++mi)
        #pragma unroll
        for (int reg = 0; reg < 4; ++reg){
          float e = __expf((s[mi][ni][reg] - m) * SCL);
          s[mi][ni][reg] = e; sum += e;
        }
      sum += __shfl_xor(sum, 16);
      sum += __shfl_xor(sum, 32);
      float rs = 1.0f / sum;
      int t = tc*32 + ni*16 + l15;
      #pragma unroll
      for (int mi = 0; mi < 4; ++mi){
        f32x4 pv;
        #pragma unroll
        for (int reg = 0; reg < 4; ++reg) pv[reg] = s[mi][ni][reg] * rs;
        store_bf4(&P[h * 4608 + t * 72 + mi*16 + l4*4], pv);
      }
    }
  }
  __syncthreads();

  // ---------------- O^T[d][t] = V^T * P^T -> O[t][c] in R0 ----------------
  {
    int wdh = h * 128 + tc * 64;
    f32x4 acc[4][4];
    #pragma unroll
    for (int i = 0; i < 4; ++i)
      #pragma unroll
      for (int j = 0; j < 4; ++j) acc[i][j] = f32x4{0.f,0.f,0.f,0.f};
    const unsigned short* P = R1;
    #pragma unroll
    for (int ks = 0; ks < 2; ++ks){
      int k0 = ks * 32 + l4 * 8;
      bf16x8 a[4], bb[4];
      #pragma unroll
      for (int mi = 0; mi < 4; ++mi)
        a[mi] = *reinterpret_cast<const bf16x8*>(&R2[(wdh + mi*16 + l15) * 72 + k0]);  // V[d][u]
      #pragma unroll
      for (int ni = 0; ni < 4; ++ni)
        bb[ni] = *reinterpret_cast<const bf16x8*>(&P[h * 4608 + (ni*16 + l15) * 72 + k0]); // P[t][u]
      #pragma unroll
      for (int mi = 0; mi < 4; ++mi)
        #pragma unroll
        for (int ni = 0; ni < 4; ++ni)
          acc[mi][ni] = MFMA16(a[mi], bb[ni], acc[mi][ni], 0, 0, 0);
    }
    #pragma unroll
    for (int mi = 0; mi < 4; ++mi){
      int c0 = wdh + mi*16 + l4*4;
      #pragma unroll
      for (int ni = 0; ni < 4; ++ni)
        store_bf4(&R0[(ni*16 + l15) * 264 + c0], acc[mi][ni]);
    }
  }
  __syncthreads();

  // ---------------- out^T = Wo * o^T ; +residual, relu, store ----------------
  {
    f32x4 acc[4][4];
    #pragma unroll
    for (int i = 0; i < 4; ++i)
      #pragma unroll
      for (int j = 0; j < 4; ++j) acc[i][j] = f32x4{0.f,0.f,0.f,0.f};
    #pragma unroll
    for (int ks = 0; ks < 8; ++ks){
      int k0 = ks * 32 + l4 * 8;
      bf16x8 a[4], bb[4];
      #pragma unroll
      for (int mi = 0; mi < 4; ++mi)
        a[mi] = *reinterpret_cast<const bf16x8*>(Wo + (size_t)((wd + mi*16 + l15) * 256 + k0));
      #pragma unroll
      for (int ni = 0; ni < 4; ++ni)
        bb[ni] = *reinterpret_cast<const bf16x8*>(&R0[(ni*16 + l15) * 264 + k0]);  // o[t][c]
      #pragma unroll
      for (int mi = 0; mi < 4; ++mi)
        #pragma unroll
        for (int ni = 0; ni < 4; ++ni)
          acc[mi][ni] = MFMA16(a[mi], bb[ni], acc[mi][ni], 0, 0, 0);
    }
    #pragma unroll
    for (int mi = 0; mi < 4; ++mi){
      #pragma unroll
      for (int ni = 0; ni < 4; ++ni){
        int t = ni*16 + l15, thi = t >> 3, twi = t & 7;
        size_t base = (size_t)(wd + mi*16 + l4*4) * HW + (size_t)thi * W + twi;
        #pragma unroll
        for (int reg = 0; reg < 4; ++reg){
          float res = xsrc[base + (size_t)reg * HW];
          float v = acc[mi][ni][reg] + res;
          outp[base + (size_t)reg * HW] = fmaxf(v, 0.f);
        }
      }
    }
  }
}

extern "C" void kernel_launch(void* const* d_in, const int* in_sizes, int n_in,
                              void* d_out, int out_size, void* d_ws, size_t ws_size,
                              hipStream_t stream) {
  (void)in_sizes; (void)n_in; (void)out_size; (void)ws_size;
  const float* f0 = (const float*)d_in[0];
  const float* f1 = (const float*)d_in[1];
  const float* f2 = (const float*)d_in[2];
  const float* f3 = (const float*)d_in[3];
  const float* w1 = (const float*)d_in[4];
  const float* w2 = (const float*)d_in[5];
  unsigned short* wbf = (unsigned short*)d_ws;   // 2*16*65536 bf16 = 4 MB
  float* out = (float*)d_out;

  wcvt_kernel<<<2048, 256, 0, stream>>>(w1, w2, wbf);
  swin_phase<<<680, 256, 0, stream>>>(f0, f1, f2, f3, wbf, out, 0);
  swin_phase<<<680, 256, 0, stream>>>(f0, f1, f2, f3, wbf, out, 1);
}